// Round 1
// baseline (5537.573 us; speedup 1.0000x reference)
//
#include <hip/hip_runtime.h>
#include <cmath>

#define BATCH 64

// ---------------------------------------------------------------------------
// Spline + silu expansion: x -> [silu(x), B_0(x) .. B_7(x)]
// Cubic B-splines on uniform knots g[j] = 0.4*j - 2.2, j = 0..11.
// Matches reference Cox-de Boor recursion exactly (fp32).
// ---------------------------------------------------------------------------
__device__ __forceinline__ void expand9(float x, float* e) {
  float t = __expf(-x);
  e[0] = __fdividef(x, 1.f + t);  // silu
  float b[11];
#pragma unroll
  for (int j = 0; j < 11; ++j) {
    float gj  = 0.4f * (float)j - 2.2f;
    float gj1 = 0.4f * (float)(j + 1) - 2.2f;
    b[j] = (x >= gj && x < gj1) ? 1.f : 0.f;
  }
#pragma unroll
  for (int k = 1; k <= 3; ++k) {
    float inv = 1.f / (0.4f * (float)k);
#pragma unroll
    for (int j = 0; j < 11 - k; ++j) {
      float gj   = 0.4f * (float)j - 2.2f;
      float gjk1 = 0.4f * (float)(j + k + 1) - 2.2f;
      b[j] = ((x - gj) * b[j] + (gjk1 - x) * b[j + 1]) * inv;
    }
  }
#pragma unroll
  for (int v = 0; v < 8; ++v) e[v + 1] = b[v];
}

// ---------------------------------------------------------------------------
// h = relu(x @ lin_w^T + lin_b)   x:[64,100] lin_w:[2048,100] -> h:[64,2048]
// ---------------------------------------------------------------------------
__global__ __launch_bounds__(256) void linear_relu_kernel(
    const float* __restrict__ x, const float* __restrict__ w,
    const float* __restrict__ bias, float* __restrict__ h) {
  int idx = blockIdx.x * 256 + threadIdx.x;  // 64*2048
  int b = idx >> 11, o = idx & 2047;
  const float* xr = x + b * 100;
  const float* wr = w + o * 100;
  float acc = bias[o];
#pragma unroll 4
  for (int k = 0; k < 100; ++k) acc += xr[k] * wr[k];
  h[idx] = fmaxf(acc, 0.f);
}

// ---------------------------------------------------------------------------
// Fused upsample2x + im2col + spline-expand + GEMM for one KAN conv layer.
// Input act: [64, CIN, HO/2, WO/2]  (upsample fused into the read)
// Output: if SK>1 partial [SK][M][COUT], else activation [64, COUT, HO, WO].
// Tile: BM=64 positions x BN cols, 256 threads, 4x4 accumulators.
// ---------------------------------------------------------------------------
template <int CIN, int COUT, int HO, int WO, int BN, int SK>
__global__ __launch_bounds__(256) void kan_gemm(
    const float* __restrict__ in, const float* __restrict__ bw,
    const float* __restrict__ sw, const float* __restrict__ ss,
    float* __restrict__ outp) {
  constexpr int BM = 64, TM = 4, TN = 4, FC = 16;
  constexpr int F = CIN * 9;
  constexpr int HI = HO / 2, WI = WO / 2;
  constexpr int M = BATCH * HO * WO;
  constexpr int FPB = F / SK;
  static_assert(FPB % FC == 0, "chunking");

  __shared__ float Ae[FC * 9][BM];

  const int t = threadIdx.x;
  const int mbase = blockIdx.x * BM;
  const int obase = blockIdx.y * BN;
  const int f0 = blockIdx.z * FPB;

  const int cg = t & (BN / TN - 1);
  const int rg = t / (BN / TN);
  const int m0 = rg * TM;
  const int o0 = obase + cg * TN;

  float acc[TM][TN];
#pragma unroll
  for (int i = 0; i < TM; ++i)
#pragma unroll
    for (int j = 0; j < TN; ++j) acc[i][j] = 0.f;

  for (int fc = f0; fc < f0 + FPB; fc += FC) {
    // ---- stage expanded A-tile into LDS ----
#pragma unroll
    for (int j = 0; j < BM * FC / 256; ++j) {
      int p = j * 256 + t;
      int ml = p & (BM - 1);
      int df = p >> 6;
      int f = fc + df;
      int c = f / 9;
      int r = f - c * 9;
      int kh = r / 3, kw = r - kh * 3;
      int m = mbase + ml;
      int bb = m / (HO * WO);
      int rem = m % (HO * WO);
      int hh = rem / WO, ww = rem % WO;
      int hp = hh + kh - 1, wp = ww + kw - 1;
      float val = 0.f;
      if (hp >= 0 && hp < HO && wp >= 0 && wp < WO)
        val = in[((bb * CIN + c) * HI + (hp >> 1)) * WI + (wp >> 1)];
      float e[9];
      expand9(val, e);
#pragma unroll
      for (int v = 0; v < 9; ++v) Ae[df * 9 + v][ml] = e[v];
    }
    __syncthreads();

    // ---- compute ----
#pragma unroll 2
    for (int df = 0; df < FC; ++df) {
      int f = fc + df;
      float wb[TN], wsv[TN][8];
#pragma unroll
      for (int tn = 0; tn < TN; ++tn) {
        int i = (o0 + tn) * F + f;
        wb[tn] = bw[i];
        float sc = ss[i];
        const float4* sp = reinterpret_cast<const float4*>(sw + (size_t)i * 8);
        float4 s0 = sp[0], s1 = sp[1];
        wsv[tn][0] = s0.x * sc; wsv[tn][1] = s0.y * sc;
        wsv[tn][2] = s0.z * sc; wsv[tn][3] = s0.w * sc;
        wsv[tn][4] = s1.x * sc; wsv[tn][5] = s1.y * sc;
        wsv[tn][6] = s1.z * sc; wsv[tn][7] = s1.w * sc;
      }
      float a[9][TM];
#pragma unroll
      for (int v = 0; v < 9; ++v) {
        float4 q = *reinterpret_cast<const float4*>(&Ae[df * 9 + v][m0]);
        a[v][0] = q.x; a[v][1] = q.y; a[v][2] = q.z; a[v][3] = q.w;
      }
#pragma unroll
      for (int tm = 0; tm < TM; ++tm)
#pragma unroll
        for (int tn = 0; tn < TN; ++tn) acc[tm][tn] += a[0][tm] * wb[tn];
#pragma unroll
      for (int v = 1; v < 9; ++v)
#pragma unroll
        for (int tm = 0; tm < TM; ++tm)
#pragma unroll
          for (int tn = 0; tn < TN; ++tn)
            acc[tm][tn] += a[v][tm] * wsv[tn][v - 1];
    }
    __syncthreads();
  }

  // ---- epilogue ----
  if constexpr (SK > 1) {
    float* p = outp + (size_t)blockIdx.z * M * COUT;
#pragma unroll
    for (int tm = 0; tm < TM; ++tm) {
      int m = mbase + m0 + tm;
#pragma unroll
      for (int tn = 0; tn < TN; ++tn)
        p[(size_t)m * COUT + (o0 + tn)] = acc[tm][tn];
    }
  } else {
#pragma unroll
    for (int tm = 0; tm < TM; ++tm) {
      int m = mbase + m0 + tm;
      int bb = m / (HO * WO);
      int rem = m % (HO * WO);
      int hh = rem / WO, ww = rem % WO;
#pragma unroll
      for (int tn = 0; tn < TN; ++tn) {
        int o = o0 + tn;
        outp[((bb * COUT + o) * HO + hh) * WO + ww] = acc[tm][tn];
      }
    }
  }
}

// ---------------------------------------------------------------------------
// Sum split-K partials [SK][M][COUT] -> activation [64, COUT, HO, WO]
// ---------------------------------------------------------------------------
template <int COUT, int HO, int WO, int SK>
__global__ __launch_bounds__(256) void reduce_partials(
    const float* __restrict__ part, float* __restrict__ act) {
  constexpr int M = BATCH * HO * WO;
  int idx = blockIdx.x * 256 + threadIdx.x;
  if (idx >= M * COUT) return;
  float s = 0.f;
#pragma unroll
  for (int k = 0; k < SK; ++k) s += part[(size_t)k * M * COUT + idx];
  int m = idx / COUT, o = idx - (idx / COUT) * COUT;
  int bb = m / (HO * WO);
  int rem = m % (HO * WO);
  int hh = rem / WO, ww = rem % WO;
  act[((bb * COUT + o) * HO + hh) * WO + ww] = s;
}

// ---------------------------------------------------------------------------
// Layer 4 (Cout=3): thread per output pixel, wave-uniform weight loads,
// fused tanh. a3: [64,64,16,16] -> out: [64,3,32,32]
// ---------------------------------------------------------------------------
__global__ __launch_bounds__(256) void kan_l4(
    const float* __restrict__ a3, const float* __restrict__ bw,
    const float* __restrict__ sw, const float* __restrict__ ss,
    float* __restrict__ out) {
  int n = blockIdx.x * 256 + threadIdx.x;  // 65536
  int b = n >> 10, rem = n & 1023, h = rem >> 5, w = rem & 31;
  float acc[3] = {0.f, 0.f, 0.f};
  for (int c = 0; c < 64; ++c) {
#pragma unroll
    for (int kh = 0; kh < 3; ++kh) {
#pragma unroll
      for (int kw = 0; kw < 3; ++kw) {
        int f = (c * 3 + kh) * 3 + kw;
        int hp = h + kh - 1, wp = w + kw - 1;
        float x = 0.f;
        if (hp >= 0 && hp < 32 && wp >= 0 && wp < 32)
          x = a3[((b * 64 + c) * 16 + (hp >> 1)) * 16 + (wp >> 1)];
        float e[9];
        expand9(x, e);
#pragma unroll
        for (int o = 0; o < 3; ++o) {
          int i = o * 576 + f;
          float d = e[1] * sw[i * 8 + 0];
#pragma unroll
          for (int v = 1; v < 8; ++v) d += e[v + 1] * sw[i * 8 + v];
          acc[o] += e[0] * bw[i] + d * ss[i];
        }
      }
    }
  }
#pragma unroll
  for (int o = 0; o < 3; ++o)
    out[((b * 3 + o) * 32 + h) * 32 + w] = tanhf(acc[o]);
}

// ---------------------------------------------------------------------------
extern "C" void kernel_launch(void* const* d_in, const int* in_sizes, int n_in,
                              void* d_out, int out_size, void* d_ws,
                              size_t ws_size, hipStream_t stream) {
  const float* x     = (const float*)d_in[0];
  const float* lin_w = (const float*)d_in[1];
  const float* lin_b = (const float*)d_in[2];
  const float* bw1 = (const float*)d_in[3];
  const float* sw1 = (const float*)d_in[4];
  const float* ss1 = (const float*)d_in[5];
  const float* bw2 = (const float*)d_in[6];
  const float* sw2 = (const float*)d_in[7];
  const float* ss2 = (const float*)d_in[8];
  const float* bw3 = (const float*)d_in[9];
  const float* sw3 = (const float*)d_in[10];
  const float* ss3 = (const float*)d_in[11];
  const float* bw4 = (const float*)d_in[12];
  const float* sw4 = (const float*)d_in[13];
  const float* ss4 = (const float*)d_in[14];

  float* h    = (float*)d_ws;                 // 64*2048
  float* a1   = h + 64 * 2048;                // 64*256*4*4
  float* a2   = a1 + 64 * 256 * 16;           // 64*128*8*8
  float* a3   = a2 + 64 * 128 * 64;           // 64*64*16*16
  float* part = a3 + 64 * 64 * 256;           // max 8*1024*256

  linear_relu_kernel<<<512, 256, 0, stream>>>(x, lin_w, lin_b, h);

  // L1: CIN=512 COUT=256 4x4, split-K=8
  kan_gemm<512, 256, 4, 4, 64, 8>
      <<<dim3(16, 4, 8), 256, 0, stream>>>(h, bw1, sw1, ss1, part);
  reduce_partials<256, 4, 4, 8><<<1024, 256, 0, stream>>>(part, a1);

  // L2: CIN=256 COUT=128 8x8, split-K=2
  kan_gemm<256, 128, 8, 8, 64, 2>
      <<<dim3(64, 2, 2), 256, 0, stream>>>(a1, bw2, sw2, ss2, part);
  reduce_partials<128, 8, 8, 2><<<2048, 256, 0, stream>>>(part, a2);

  // L3: CIN=128 COUT=64 16x16, no split
  kan_gemm<128, 64, 16, 16, 64, 1>
      <<<dim3(256, 1, 1), 256, 0, stream>>>(a2, bw3, sw3, ss3, a3);

  // L4: CIN=64 COUT=3 32x32 + tanh
  kan_l4<<<256, 256, 0, stream>>>(a3, bw4, sw4, ss4, (float*)d_out);
}

// Round 2
// 1553.882 us; speedup vs baseline: 3.5637x; 3.5637x over previous
//
#include <hip/hip_runtime.h>
#include <cmath>

#define BATCH 64

// ---------------------------------------------------------------------------
// Spline + silu expansion: x -> [silu(x), B_0(x) .. B_7(x)]
// ---------------------------------------------------------------------------
__device__ __forceinline__ void expand9(float x, float* e) {
  float t = __expf(-x);
  e[0] = __fdividef(x, 1.f + t);  // silu
  float b[11];
#pragma unroll
  for (int j = 0; j < 11; ++j) {
    float gj  = 0.4f * (float)j - 2.2f;
    float gj1 = 0.4f * (float)(j + 1) - 2.2f;
    b[j] = (x >= gj && x < gj1) ? 1.f : 0.f;
  }
#pragma unroll
  for (int k = 1; k <= 3; ++k) {
    float inv = 1.f / (0.4f * (float)k);
#pragma unroll
    for (int j = 0; j < 11 - k; ++j) {
      float gj   = 0.4f * (float)j - 2.2f;
      float gjk1 = 0.4f * (float)(j + k + 1) - 2.2f;
      b[j] = ((x - gj) * b[j] + (gjk1 - x) * b[j + 1]) * inv;
    }
  }
#pragma unroll
  for (int v = 0; v < 8; ++v) e[v + 1] = b[v];
}

// ---------------------------------------------------------------------------
__global__ __launch_bounds__(256) void linear_relu_kernel(
    const float* __restrict__ x, const float* __restrict__ w,
    const float* __restrict__ bias, float* __restrict__ h) {
  int idx = blockIdx.x * 256 + threadIdx.x;  // 64*2048
  int b = idx >> 11, o = idx & 2047;
  const float* xr = x + b * 100;
  const float* wr = w + o * 100;
  float acc = bias[o];
#pragma unroll 4
  for (int k = 0; k < 100; ++k) acc += xr[k] * wr[k];
  h[idx] = fmaxf(acc, 0.f);
}

// ---------------------------------------------------------------------------
// Expanded-weight prep: Bexp[(f*9+v)*N + o] = v==0 ? bw[o,f] : sw[o,f,v-1]*ss[o,f]
// ---------------------------------------------------------------------------
template <int F, int N>
__global__ __launch_bounds__(256) void prep_bexp(
    const float* __restrict__ bw, const float* __restrict__ sw,
    const float* __restrict__ ss, float* __restrict__ Bexp) {
  int idx = blockIdx.x * 256 + threadIdx.x;  // over F*9*N (exact multiple of 256)
  int o = idx & (N - 1);
  int kv = idx / N;
  int f = kv / 9, v = kv - 9 * f;
  float w;
  if (v == 0)
    w = bw[o * F + f];
  else
    w = sw[((size_t)(o * F + f)) * 8 + (v - 1)] * ss[o * F + f];
  Bexp[idx] = w;
}

// ---------------------------------------------------------------------------
// Expanded GEMM: C[M, COUT] += A[M, K] * Bexp[K, COUT], K = 81*CIN.
// A generated on the fly (upsample + im2col + spline expansion) into LDS.
// 256 threads, 8x8 per-thread tile, split-frag float4 mapping (conflict-free).
// Writes split-K partials part[z][M][COUT].
// ---------------------------------------------------------------------------
template <int CIN, int COUT, int HO, int WO, int BM, int BN, int SK>
__global__ __launch_bounds__(256, 2) void gemm_exp(
    const float* __restrict__ in, const float* __restrict__ Bexp,
    float* __restrict__ part) {
  constexpr int BK = 18;                 // 2 features per chunk
  constexpr int K = CIN * 81;
  constexpr int HI = HO / 2, WI = WO / 2;
  constexpr int M = BATCH * HO * WO;
  constexpr int KR = K / SK;
  constexpr int NCH = KR / BK;
  static_assert(KR % BK == 0, "K split alignment");
  constexpr int TX = BN / 8, TY = BM / 8;
  static_assert(TX * TY == 256, "thread tile");

  __shared__ float As[BK * BM];
  __shared__ float Bs[BK * BN];

  const int t = threadIdx.x;
  const int tx = t % TX, ty = t / TX;
  const int mbase = blockIdx.x * BM;
  const int nbase = blockIdx.y * BN;
  const int k0 = blockIdx.z * KR;

  float acc[8][8] = {};

  for (int ch = 0; ch < NCH; ++ch) {
    const int kg = k0 + ch * BK;
    const int fbase = kg / 9;  // exact (kg multiple of 9)

    // ---- A staging: expand 2 features x BM positions ----
#pragma unroll
    for (int i = 0; i < (2 * BM) / 256; ++i) {
      int task = i * 256 + t;
      int ml = task >> 1, fp = task & 1;
      int f = fbase + fp;
      int c = f / 9, r = f - 9 * c;
      int kh = r / 3, kw = r - kh * 3;
      int m = mbase + ml;
      int b = m / (HO * WO), hw = m % (HO * WO);
      int hh = hw / WO, ww = hw % WO;
      int hp = hh + kh - 1, wp = ww + kw - 1;
      float val = 0.f;
      if ((unsigned)hp < (unsigned)HO && (unsigned)wp < (unsigned)WO)
        val = in[((b * CIN + c) * HI + (hp >> 1)) * WI + (wp >> 1)];
      float e[9];
      expand9(val, e);
#pragma unroll
      for (int v = 0; v < 9; ++v) As[(fp * 9 + v) * BM + ml] = e[v];
    }

    // ---- B staging: 18 rows x BN cols, coalesced float4 ----
    constexpr int BV = BK * BN / 4;
#pragma unroll
    for (int p = t; p < BV; p += 256) {
      int row = p / (BN / 4), c4 = p - row * (BN / 4);
      float4 v = *reinterpret_cast<const float4*>(
          &Bexp[(size_t)(kg + row) * COUT + nbase + c4 * 4]);
      *reinterpret_cast<float4*>(&Bs[row * BN + c4 * 4]) = v;
    }
    __syncthreads();

#pragma unroll 6
    for (int k = 0; k < BK; ++k) {
      float4 a0 = *reinterpret_cast<const float4*>(&As[k * BM + ty * 4]);
      float4 a1 = *reinterpret_cast<const float4*>(&As[k * BM + BM / 2 + ty * 4]);
      float4 b0 = *reinterpret_cast<const float4*>(&Bs[k * BN + tx * 4]);
      float4 b1 = *reinterpret_cast<const float4*>(&Bs[k * BN + BN / 2 + tx * 4]);
      float av[8] = {a0.x, a0.y, a0.z, a0.w, a1.x, a1.y, a1.z, a1.w};
      float bv[8] = {b0.x, b0.y, b0.z, b0.w, b1.x, b1.y, b1.z, b1.w};
#pragma unroll
      for (int i2 = 0; i2 < 8; ++i2)
#pragma unroll
        for (int j2 = 0; j2 < 8; ++j2)
          acc[i2][j2] = fmaf(av[i2], bv[j2], acc[i2][j2]);
    }
    __syncthreads();
  }

  // ---- epilogue: split-K partials, float4 stores ----
  float* p = part + (size_t)blockIdx.z * M * COUT;
#pragma unroll
  for (int hf = 0; hf < 2; ++hf)
#pragma unroll
    for (int im = 0; im < 4; ++im) {
      int gm = mbase + hf * (BM / 2) + ty * 4 + im;
      float4 v0 = {acc[hf * 4 + im][0], acc[hf * 4 + im][1],
                   acc[hf * 4 + im][2], acc[hf * 4 + im][3]};
      float4 v1 = {acc[hf * 4 + im][4], acc[hf * 4 + im][5],
                   acc[hf * 4 + im][6], acc[hf * 4 + im][7]};
      *reinterpret_cast<float4*>(&p[(size_t)gm * COUT + nbase + tx * 4]) = v0;
      *reinterpret_cast<float4*>(
          &p[(size_t)gm * COUT + nbase + BN / 2 + tx * 4]) = v1;
    }
}

// ---------------------------------------------------------------------------
// Reduce split-K partials into activation layout [B][COUT][HO][WO].
// Output-index-major -> coalesced writes; reads are L1/L2 resident.
// ---------------------------------------------------------------------------
template <int COUT, int HO, int WO>
__global__ __launch_bounds__(256) void reduce_p(
    const float* __restrict__ part, float* __restrict__ act, int SK) {
  constexpr int M = BATCH * HO * WO;
  int idx = blockIdx.x * 256 + threadIdx.x;  // over M*COUT
  int ww = idx % WO;
  int tmp = idx / WO;
  int hh = tmp % HO;
  tmp /= HO;
  int o = tmp % COUT;
  int b = tmp / COUT;
  int m = (b * HO + hh) * WO + ww;
  float s = 0.f;
  for (int k = 0; k < SK; ++k) s += part[((size_t)k * M + m) * COUT + o];
  act[idx] = s;
}

// ---------------------------------------------------------------------------
// L4 (Cout=3) split 4-way over channels; partials then fused tanh reduce.
// ---------------------------------------------------------------------------
__global__ __launch_bounds__(256) void kan_l4_split(
    const float* __restrict__ a3, const float* __restrict__ bw,
    const float* __restrict__ sw, const float* __restrict__ ss,
    float* __restrict__ p4) {
  int tid = blockIdx.x * 256 + threadIdx.x;  // 4*65536
  int cs = tid >> 16, pix = tid & 65535;
  int b = pix >> 10, rem = pix & 1023, h = rem >> 5, w = rem & 31;
  float acc[3] = {0.f, 0.f, 0.f};
  for (int c = cs * 16; c < cs * 16 + 16; ++c) {
#pragma unroll
    for (int kh = 0; kh < 3; ++kh) {
#pragma unroll
      for (int kw = 0; kw < 3; ++kw) {
        int f = (c * 3 + kh) * 3 + kw;
        int hp = h + kh - 1, wp = w + kw - 1;
        float x = 0.f;
        if ((unsigned)hp < 32u && (unsigned)wp < 32u)
          x = a3[((b * 64 + c) * 16 + (hp >> 1)) * 16 + (wp >> 1)];
        float e[9];
        expand9(x, e);
#pragma unroll
        for (int o = 0; o < 3; ++o) {
          int i = o * 576 + f;
          float d = e[1] * sw[i * 8 + 0];
#pragma unroll
          for (int v = 1; v < 8; ++v) d += e[v + 1] * sw[i * 8 + v];
          acc[o] += e[0] * bw[i] + d * ss[i];
        }
      }
    }
  }
#pragma unroll
  for (int o = 0; o < 3; ++o)
    p4[cs * 196608 + ((b * 3 + o) << 10) + (h << 5) + w] = acc[o];
}

__global__ __launch_bounds__(256) void reduce_tanh_l4(
    const float* __restrict__ p4, float* __restrict__ out) {
  int i = blockIdx.x * 256 + threadIdx.x;  // 196608
  float s = p4[i] + p4[i + 196608] + p4[i + 2 * 196608] + p4[i + 3 * 196608];
  out[i] = tanhf(s);
}

// ---------------------------------------------------------------------------
// Fallback (round-1 proven path) for small workspace
// ---------------------------------------------------------------------------
template <int CIN, int COUT, int HO, int WO, int BN, int SK>
__global__ __launch_bounds__(256) void kan_gemm(
    const float* __restrict__ in, const float* __restrict__ bw,
    const float* __restrict__ sw, const float* __restrict__ ss,
    float* __restrict__ outp) {
  constexpr int BM = 64, TM = 4, TN = 4, FC = 16;
  constexpr int F = CIN * 9;
  constexpr int HI = HO / 2, WI = WO / 2;
  constexpr int M = BATCH * HO * WO;
  constexpr int FPB = F / SK;

  __shared__ float Ae[FC * 9][BM];

  const int t = threadIdx.x;
  const int mbase = blockIdx.x * BM;
  const int obase = blockIdx.y * BN;
  const int f0 = blockIdx.z * FPB;

  const int cg = t & (BN / TN - 1);
  const int rg = t / (BN / TN);
  const int m0 = rg * TM;
  const int o0 = obase + cg * TN;

  float acc[TM][TN] = {};

  for (int fc = f0; fc < f0 + FPB; fc += FC) {
#pragma unroll
    for (int j = 0; j < BM * FC / 256; ++j) {
      int p = j * 256 + t;
      int ml = p & (BM - 1);
      int df = p >> 6;
      int f = fc + df;
      int c = f / 9;
      int r = f - c * 9;
      int kh = r / 3, kw = r - kh * 3;
      int m = mbase + ml;
      int bb = m / (HO * WO);
      int rem = m % (HO * WO);
      int hh = rem / WO, ww = rem % WO;
      int hp = hh + kh - 1, wp = ww + kw - 1;
      float val = 0.f;
      if (hp >= 0 && hp < HO && wp >= 0 && wp < WO)
        val = in[((bb * CIN + c) * HI + (hp >> 1)) * WI + (wp >> 1)];
      float e[9];
      expand9(val, e);
#pragma unroll
      for (int v = 0; v < 9; ++v) Ae[df * 9 + v][ml] = e[v];
    }
    __syncthreads();

#pragma unroll 2
    for (int df = 0; df < FC; ++df) {
      int f = fc + df;
      float wb[TN], wsv[TN][8];
#pragma unroll
      for (int tn = 0; tn < TN; ++tn) {
        int i = (o0 + tn) * F + f;
        wb[tn] = bw[i];
        float sc = ss[i];
        const float4* sp = reinterpret_cast<const float4*>(sw + (size_t)i * 8);
        float4 s0 = sp[0], s1 = sp[1];
        wsv[tn][0] = s0.x * sc; wsv[tn][1] = s0.y * sc;
        wsv[tn][2] = s0.z * sc; wsv[tn][3] = s0.w * sc;
        wsv[tn][4] = s1.x * sc; wsv[tn][5] = s1.y * sc;
        wsv[tn][6] = s1.z * sc; wsv[tn][7] = s1.w * sc;
      }
      float a[9][TM];
#pragma unroll
      for (int v = 0; v < 9; ++v) {
        float4 q = *reinterpret_cast<const float4*>(&Ae[df * 9 + v][m0]);
        a[v][0] = q.x; a[v][1] = q.y; a[v][2] = q.z; a[v][3] = q.w;
      }
#pragma unroll
      for (int tm = 0; tm < TM; ++tm)
#pragma unroll
        for (int tn = 0; tn < TN; ++tn) acc[tm][tn] += a[0][tm] * wb[tn];
#pragma unroll
      for (int v = 1; v < 9; ++v)
#pragma unroll
        for (int tm = 0; tm < TM; ++tm)
#pragma unroll
          for (int tn = 0; tn < TN; ++tn)
            acc[tm][tn] += a[v][tm] * wsv[tn][v - 1];
    }
    __syncthreads();
  }

  if constexpr (SK > 1) {
    float* p = outp + (size_t)blockIdx.z * M * COUT;
#pragma unroll
    for (int tm = 0; tm < TM; ++tm) {
      int m = mbase + m0 + tm;
#pragma unroll
      for (int tn = 0; tn < TN; ++tn)
        p[(size_t)m * COUT + (o0 + tn)] = acc[tm][tn];
    }
  } else {
#pragma unroll
    for (int tm = 0; tm < TM; ++tm) {
      int m = mbase + m0 + tm;
      int bb = m / (HO * WO);
      int rem = m % (HO * WO);
      int hh = rem / WO, ww = rem % WO;
#pragma unroll
      for (int tn = 0; tn < TN; ++tn) {
        int o = o0 + tn;
        outp[((bb * COUT + o) * HO + hh) * WO + ww] = acc[tm][tn];
      }
    }
  }
}

template <int COUT, int HO, int WO, int SK>
__global__ __launch_bounds__(256) void reduce_partials_old(
    const float* __restrict__ part, float* __restrict__ act) {
  constexpr int M = BATCH * HO * WO;
  int idx = blockIdx.x * 256 + threadIdx.x;
  if (idx >= M * COUT) return;
  float s = 0.f;
#pragma unroll
  for (int k = 0; k < SK; ++k) s += part[(size_t)k * M * COUT + idx];
  int m = idx / COUT, o = idx - (idx / COUT) * COUT;
  int bb = m / (HO * WO);
  int rem = m % (HO * WO);
  int hh = rem / WO, ww = rem % WO;
  act[((bb * COUT + o) * HO + hh) * WO + ww] = s;
}

// ---------------------------------------------------------------------------
template <int SK1, int SK2, int SK3>
static void run_main(const float* h, float* a1, float* a2, float* a3,
                     float* part, float* bexp,
                     const float* bw1, const float* sw1, const float* ss1,
                     const float* bw2, const float* sw2, const float* ss2,
                     const float* bw3, const float* sw3, const float* ss3,
                     hipStream_t stream) {
  // L1: CIN=512 COUT=256 4x4
  prep_bexp<4608, 256><<<41472, 256, 0, stream>>>(bw1, sw1, ss1, bexp);
  gemm_exp<512, 256, 4, 4, 128, 128, SK1>
      <<<dim3(8, 2, SK1), 256, 0, stream>>>(h, bexp, part);
  reduce_p<256, 4, 4><<<1024, 256, 0, stream>>>(part, a1, SK1);
  // L2: CIN=256 COUT=128 8x8
  prep_bexp<2304, 128><<<10368, 256, 0, stream>>>(bw2, sw2, ss2, bexp);
  gemm_exp<256, 128, 8, 8, 128, 128, SK2>
      <<<dim3(32, 1, SK2), 256, 0, stream>>>(a1, bexp, part);
  reduce_p<128, 8, 8><<<2048, 256, 0, stream>>>(part, a2, SK2);
  // L3: CIN=128 COUT=64 16x16
  prep_bexp<1152, 64><<<2592, 256, 0, stream>>>(bw3, sw3, ss3, bexp);
  gemm_exp<128, 64, 16, 16, 256, 64, SK3>
      <<<dim3(64, 1, SK3), 256, 0, stream>>>(a2, bexp, part);
  reduce_p<64, 16, 16><<<4096, 256, 0, stream>>>(part, a3, SK3);
}

extern "C" void kernel_launch(void* const* d_in, const int* in_sizes, int n_in,
                              void* d_out, int out_size, void* d_ws,
                              size_t ws_size, hipStream_t stream) {
  const float* x     = (const float*)d_in[0];
  const float* lin_w = (const float*)d_in[1];
  const float* lin_b = (const float*)d_in[2];
  const float* bw1 = (const float*)d_in[3];
  const float* sw1 = (const float*)d_in[4];
  const float* ss1 = (const float*)d_in[5];
  const float* bw2 = (const float*)d_in[6];
  const float* sw2 = (const float*)d_in[7];
  const float* ss2 = (const float*)d_in[8];
  const float* bw3 = (const float*)d_in[9];
  const float* sw3 = (const float*)d_in[10];
  const float* ss3 = (const float*)d_in[11];
  const float* bw4 = (const float*)d_in[12];
  const float* sw4 = (const float*)d_in[13];
  const float* ss4 = (const float*)d_in[14];

  float* wsf = (float*)d_ws;
  float* h  = wsf;                 // 131072
  float* a1 = h + 131072;          // 262144
  float* a2 = a1 + 262144;         // 524288
  float* a3 = a2 + 524288;         // 1048576
  float* part = a3 + 1048576;
  const size_t baseFloats = 1966080;
  size_t availFloats = ws_size / 4 > baseFloats ? ws_size / 4 - baseFloats : 0;
  const size_t bexpFloats = 10616832;  // L1 Bexp (largest)

  linear_relu_kernel<<<512, 256, 0, stream>>>(x, lin_w, lin_b, h);

  bool mainPath = true;
  if (availFloats >= 8388608 + bexpFloats) {
    float* bexp = part + 8388608;
    run_main<32, 16, 8>(h, a1, a2, a3, part, bexp, bw1, sw1, ss1, bw2, sw2,
                        ss2, bw3, sw3, ss3, stream);
  } else if (availFloats >= 4194304 + bexpFloats) {
    float* bexp = part + 4194304;
    run_main<16, 8, 4>(h, a1, a2, a3, part, bexp, bw1, sw1, ss1, bw2, sw2,
                       ss2, bw3, sw3, ss3, stream);
  } else if (availFloats >= 2097152 + bexpFloats) {
    float* bexp = part + 2097152;
    run_main<8, 4, 2>(h, a1, a2, a3, part, bexp, bw1, sw1, ss1, bw2, sw2,
                      ss2, bw3, sw3, ss3, stream);
  } else {
    mainPath = false;
    // round-1 proven fallback (needs 16.3 MB)
    kan_gemm<512, 256, 4, 4, 64, 8>
        <<<dim3(16, 4, 8), 256, 0, stream>>>(h, bw1, sw1, ss1, part);
    reduce_partials_old<256, 4, 4, 8><<<1024, 256, 0, stream>>>(part, a1);
    kan_gemm<256, 128, 8, 8, 64, 2>
        <<<dim3(64, 2, 2), 256, 0, stream>>>(a1, bw2, sw2, ss2, part);
    reduce_partials_old<128, 8, 8, 2><<<2048, 256, 0, stream>>>(part, a2);
    kan_gemm<128, 64, 16, 16, 64, 1>
        <<<dim3(256, 1, 1), 256, 0, stream>>>(a2, bw3, sw3, ss3, a3);
  }
  (void)mainPath;

  // L4: split over channels + fused tanh reduce (reuses part region, 3 MB)
  kan_l4_split<<<1024, 256, 0, stream>>>(a3, bw4, sw4, ss4, part);
  reduce_tanh_l4<<<768, 256, 0, stream>>>(part, (float*)d_out);
}

// Round 4
// 1453.531 us; speedup vs baseline: 3.8097x; 1.0690x over previous
//
#include <hip/hip_runtime.h>
#include <cmath>

#define BATCH 64

// ---------------------------------------------------------------------------
// Spline + silu expansion: x -> [silu(x), B_0(x) .. B_7(x)]
// ---------------------------------------------------------------------------
__device__ __forceinline__ void expand9(float x, float* e) {
  float t = __expf(-x);
  e[0] = __fdividef(x, 1.f + t);  // silu
  float b[11];
#pragma unroll
  for (int j = 0; j < 11; ++j) {
    float gj  = 0.4f * (float)j - 2.2f;
    float gj1 = 0.4f * (float)(j + 1) - 2.2f;
    b[j] = (x >= gj && x < gj1) ? 1.f : 0.f;
  }
#pragma unroll
  for (int k = 1; k <= 3; ++k) {
    float inv = 1.f / (0.4f * (float)k);
#pragma unroll
    for (int j = 0; j < 11 - k; ++j) {
      float gj   = 0.4f * (float)j - 2.2f;
      float gjk1 = 0.4f * (float)(j + k + 1) - 2.2f;
      b[j] = ((x - gj) * b[j] + (gjk1 - x) * b[j + 1]) * inv;
    }
  }
#pragma unroll
  for (int v = 0; v < 8; ++v) e[v + 1] = b[v];
}

// ---------------------------------------------------------------------------
__global__ __launch_bounds__(256) void linear_relu_kernel(
    const float* __restrict__ x, const float* __restrict__ w,
    const float* __restrict__ bias, float* __restrict__ h) {
  int idx = blockIdx.x * 256 + threadIdx.x;  // 64*2048
  int b = idx >> 11, o = idx & 2047;
  const float* xr = x + b * 100;
  const float* wr = w + o * 100;
  float acc = bias[o];
#pragma unroll 4
  for (int k = 0; k < 100; ++k) acc += xr[k] * wr[k];
  h[idx] = fmaxf(acc, 0.f);
}

// ---------------------------------------------------------------------------
// Coalesced expanded-weight prep via LDS transpose tile (64 o x 8 f).
// Bexp[(f*9+v)*N + o] = v==0 ? bw[o,f] : sw[o,f,v-1]*ss[o,f]
// ---------------------------------------------------------------------------
template <int F, int N>
__global__ __launch_bounds__(256) void prep_bexp_t(
    const float* __restrict__ bw, const float* __restrict__ sw,
    const float* __restrict__ ss, float* __restrict__ Bexp) {
  __shared__ float tile[72][65];
  constexpr int NB = N / 64;
  const int t = threadIdx.x;
  const int ob = (blockIdx.x % NB) * 64;
  const int f0 = (blockIdx.x / NB) * 8;
  const int ol = t >> 2;
  const int o = ob + ol;
  const int g = t & 3;

#pragma unroll
  for (int q = 0; q < 2; ++q) {
    int fl = g * 2 + q;
    int f = f0 + fl;
    float bv = bw[(size_t)o * F + f];
    float sc = ss[(size_t)o * F + f];
    const float4* sp =
        reinterpret_cast<const float4*>(sw + ((size_t)o * F + f) * 8);
    float4 s0 = sp[0], s1 = sp[1];
    tile[fl * 9 + 0][ol] = bv;
    tile[fl * 9 + 1][ol] = s0.x * sc;
    tile[fl * 9 + 2][ol] = s0.y * sc;
    tile[fl * 9 + 3][ol] = s0.z * sc;
    tile[fl * 9 + 4][ol] = s0.w * sc;
    tile[fl * 9 + 5][ol] = s1.x * sc;
    tile[fl * 9 + 6][ol] = s1.y * sc;
    tile[fl * 9 + 7][ol] = s1.z * sc;
    tile[fl * 9 + 8][ol] = s1.w * sc;
  }
  __syncthreads();
#pragma unroll
  for (int r = 0; r < 18; ++r) {
    int p = r * 256 + t;
    int kv = p >> 6, oo = p & 63;
    Bexp[(size_t)(f0 * 9 + kv) * N + ob + oo] = tile[kv][oo];
  }
}

// ---------------------------------------------------------------------------
// Expanded GEMM: C[M, COUT] += A[M, K] * Bexp[K, COUT], K = 81*CIN.
// ---------------------------------------------------------------------------
template <int CIN, int COUT, int HO, int WO, int BM, int BN, int SK>
__global__ __launch_bounds__(256, 2) void gemm_exp(
    const float* __restrict__ in, const float* __restrict__ Bexp,
    float* __restrict__ part) {
  constexpr int BK = 18;
  constexpr int K = CIN * 81;
  constexpr int HI = HO / 2, WI = WO / 2;
  constexpr int M = BATCH * HO * WO;
  constexpr int KR = K / SK;
  constexpr int NCH = KR / BK;
  static_assert(KR % BK == 0, "K split alignment");
  constexpr int TX = BN / 8, TY = BM / 8;
  static_assert(TX * TY == 256, "thread tile");

  __shared__ float As[BK * BM];
  __shared__ float Bs[BK * BN];

  const int t = threadIdx.x;
  const int tx = t % TX, ty = t / TX;
  const int mbase = blockIdx.x * BM;
  const int nbase = blockIdx.y * BN;
  const int k0 = blockIdx.z * KR;

  float acc[8][8] = {};

  for (int ch = 0; ch < NCH; ++ch) {
    const int kg = k0 + ch * BK;
    const int fbase = kg / 9;

#pragma unroll
    for (int i = 0; i < (2 * BM) / 256; ++i) {
      int task = i * 256 + t;
      int ml = task >> 1, fp = task & 1;
      int f = fbase + fp;
      int c = f / 9, r = f - 9 * c;
      int kh = r / 3, kw = r - kh * 3;
      int m = mbase + ml;
      int b = m / (HO * WO), hw = m % (HO * WO);
      int hh = hw / WO, ww = hw % WO;
      int hp = hh + kh - 1, wp = ww + kw - 1;
      float val = 0.f;
      if ((unsigned)hp < (unsigned)HO && (unsigned)wp < (unsigned)WO)
        val = in[((b * CIN + c) * HI + (hp >> 1)) * WI + (wp >> 1)];
      float e[9];
      expand9(val, e);
#pragma unroll
      for (int v = 0; v < 9; ++v) As[(fp * 9 + v) * BM + ml] = e[v];
    }

    constexpr int BV = BK * BN / 4;
#pragma unroll
    for (int p = t; p < BV; p += 256) {
      int row = p / (BN / 4), c4 = p - row * (BN / 4);
      float4 v = *reinterpret_cast<const float4*>(
          &Bexp[(size_t)(kg + row) * COUT + nbase + c4 * 4]);
      *reinterpret_cast<float4*>(&Bs[row * BN + c4 * 4]) = v;
    }
    __syncthreads();

#pragma unroll 6
    for (int k = 0; k < BK; ++k) {
      float4 a0 = *reinterpret_cast<const float4*>(&As[k * BM + ty * 4]);
      float4 a1 = *reinterpret_cast<const float4*>(&As[k * BM + BM / 2 + ty * 4]);
      float4 b0 = *reinterpret_cast<const float4*>(&Bs[k * BN + tx * 4]);
      float4 b1 = *reinterpret_cast<const float4*>(&Bs[k * BN + BN / 2 + tx * 4]);
      float av[8] = {a0.x, a0.y, a0.z, a0.w, a1.x, a1.y, a1.z, a1.w};
      float bv[8] = {b0.x, b0.y, b0.z, b0.w, b1.x, b1.y, b1.z, b1.w};
#pragma unroll
      for (int i2 = 0; i2 < 8; ++i2)
#pragma unroll
        for (int j2 = 0; j2 < 8; ++j2)
          acc[i2][j2] = fmaf(av[i2], bv[j2], acc[i2][j2]);
    }
    __syncthreads();
  }

  float* p = part + (size_t)blockIdx.z * M * COUT;
#pragma unroll
  for (int hf = 0; hf < 2; ++hf)
#pragma unroll
    for (int im = 0; im < 4; ++im) {
      int gm = mbase + hf * (BM / 2) + ty * 4 + im;
      float4 v0 = {acc[hf * 4 + im][0], acc[hf * 4 + im][1],
                   acc[hf * 4 + im][2], acc[hf * 4 + im][3]};
      float4 v1 = {acc[hf * 4 + im][4], acc[hf * 4 + im][5],
                   acc[hf * 4 + im][6], acc[hf * 4 + im][7]};
      *reinterpret_cast<float4*>(&p[(size_t)gm * COUT + nbase + tx * 4]) = v0;
      *reinterpret_cast<float4*>(
          &p[(size_t)gm * COUT + nbase + BN / 2 + tx * 4]) = v1;
    }
}

// ---------------------------------------------------------------------------
template <int COUT, int HO, int WO>
__global__ __launch_bounds__(256) void reduce_p(
    const float* __restrict__ part, float* __restrict__ act, int SK) {
  constexpr int M = BATCH * HO * WO;
  int idx = blockIdx.x * 256 + threadIdx.x;
  int ww = idx % WO;
  int tmp = idx / WO;
  int hh = tmp % HO;
  tmp /= HO;
  int o = tmp % COUT;
  int b = tmp / COUT;
  int m = (b * HO + hh) * WO + ww;
  float s = 0.f;
  for (int k = 0; k < SK; ++k) s += part[((size_t)k * M + m) * COUT + o];
  act[idx] = s;
}

// ---------------------------------------------------------------------------
// L4 v2: precomputed expansion E[b][c][16][16][12] + fused-weight consumer.
// FIX (round 3): out-of-bounds taps use expand9(0), NOT zeros — reference
// pads patch VALUES with 0 before spline expansion, and b_splines(0) != 0.
// ---------------------------------------------------------------------------
__global__ __launch_bounds__(256) void l4_expand(
    const float* __restrict__ a3, float* __restrict__ E) {
  int idx = blockIdx.x * 256 + threadIdx.x;  // 64*64*256
  float x = a3[idx];
  float e[9];
  expand9(x, e);
  float4* p = reinterpret_cast<float4*>(E + (size_t)idx * 12);
  p[0] = make_float4(e[0], e[1], e[2], e[3]);
  p[1] = make_float4(e[4], e[5], e[6], e[7]);
  p[2] = make_float4(e[8], 0.f, 0.f, 0.f);
}

__global__ __launch_bounds__(256) void prep_wl4(
    const float* __restrict__ bw, const float* __restrict__ sw,
    const float* __restrict__ ss, float* __restrict__ W) {
  int idx = blockIdx.x * 256 + threadIdx.x;  // 576*9*3 = 15552
  if (idx >= 15552) return;
  int o = idx % 3;
  int rest = idx / 3;
  int v = rest % 9;
  int f = rest / 9;
  float w = (v == 0) ? bw[o * 576 + f]
                     : sw[((size_t)(o * 576 + f)) * 8 + (v - 1)] * ss[o * 576 + f];
  W[idx] = w;
}

__device__ __forceinline__ void l4_load(const float* __restrict__ base,
                                        const float* __restrict__ ez,
                                        int gi0, int gj0, bool vr0, bool vr1,
                                        bool vc0, bool vc1, float e[2][2][12]) {
#pragma unroll
  for (int a = 0; a < 2; ++a)
#pragma unroll
    for (int b2 = 0; b2 < 2; ++b2) {
      bool ok = (a ? vr1 : vr0) && (b2 ? vc1 : vc0);
      if (ok) {
        const float4* p = reinterpret_cast<const float4*>(
            base + ((gi0 + a) * 16 + (gj0 + b2)) * 12);
        float4 q0 = p[0], q1 = p[1], q2 = p[2];
        e[a][b2][0] = q0.x; e[a][b2][1] = q0.y; e[a][b2][2] = q0.z;
        e[a][b2][3] = q0.w; e[a][b2][4] = q1.x; e[a][b2][5] = q1.y;
        e[a][b2][6] = q1.z; e[a][b2][7] = q1.w; e[a][b2][8] = q2.x;
      } else {
#pragma unroll
        for (int v = 0; v < 9; ++v) e[a][b2][v] = ez[v];
      }
    }
}

template <int PH, int PW>
__device__ __forceinline__ void l4_compute(const float e[2][2][12],
                                           const float* __restrict__ wc,
                                           float acc[3]) {
#pragma unroll
  for (int kh = 0; kh < 3; ++kh) {
    const int sh = (kh > PH) ? 1 : 0;
#pragma unroll
    for (int kw = 0; kw < 3; ++kw) {
      const int sw_ = (kw > PW) ? 1 : 0;
      const float* wp = wc + (kh * 3 + kw) * 27;
#pragma unroll
      for (int v = 0; v < 9; ++v) {
        float ev = e[sh][sw_][v];
        acc[0] = fmaf(ev, wp[v * 3 + 0], acc[0]);
        acc[1] = fmaf(ev, wp[v * 3 + 1], acc[1]);
        acc[2] = fmaf(ev, wp[v * 3 + 2], acc[2]);
      }
    }
  }
}

template <int PH, int PW>
__device__ __forceinline__ void l4_acc(const float* __restrict__ E,
                                       const float* __restrict__ W,
                                       const float* __restrict__ ez, int bb,
                                       int gi0, int gj0, float acc[3]) {
  const bool vr0 = (unsigned)gi0 < 16u, vr1 = (unsigned)(gi0 + 1) < 16u;
  const bool vc0 = (unsigned)gj0 < 16u, vc1 = (unsigned)(gj0 + 1) < 16u;
  const float* base0 = E + (size_t)bb * 64 * 3072;
  float eA[2][2][12], eB[2][2][12];
  l4_load(base0, ez, gi0, gj0, vr0, vr1, vc0, vc1, eA);
  for (int c = 0; c < 64; c += 2) {
    l4_load(base0 + (c + 1) * 3072, ez, gi0, gj0, vr0, vr1, vc0, vc1, eB);
    l4_compute<PH, PW>(eA, W + c * 243, acc);
    if (c + 2 < 64)
      l4_load(base0 + (c + 2) * 3072, ez, gi0, gj0, vr0, vr1, vc0, vc1, eA);
    l4_compute<PH, PW>(eB, W + (c + 1) * 243, acc);
  }
}

__global__ __launch_bounds__(256) void kan_l4_v2(
    const float* __restrict__ E, const float* __restrict__ W,
    float* __restrict__ out) {
  const int bb = blockIdx.x >> 2, tile = blockIdx.x & 3;
  const int th = tile >> 1, tw = tile & 1;
  const int t = threadIdx.x, wave = t >> 6, lane = t & 63;
  const int i = lane >> 3, j = lane & 7;
  const int ph = wave >> 1, pw = wave & 1;
  const int h = th * 16 + 2 * i + ph, w = tw * 16 + 2 * j + pw;
  const int gi0 = th * 8 + i + ph - 1, gj0 = tw * 8 + j + pw - 1;
  float ez[9];
  expand9(0.f, ez);  // expansion of a padded zero (b_splines(0) != 0)
  float acc[3] = {0.f, 0.f, 0.f};
  if (wave == 0)
    l4_acc<0, 0>(E, W, ez, bb, gi0, gj0, acc);
  else if (wave == 1)
    l4_acc<0, 1>(E, W, ez, bb, gi0, gj0, acc);
  else if (wave == 2)
    l4_acc<1, 0>(E, W, ez, bb, gi0, gj0, acc);
  else
    l4_acc<1, 1>(E, W, ez, bb, gi0, gj0, acc);
#pragma unroll
  for (int o = 0; o < 3; ++o)
    out[((bb * 3 + o) * 32 + h) * 32 + w] = tanhf(acc[o]);
}

// ---------------------------------------------------------------------------
// Fallback path (round-1/2 proven) for small workspace
// ---------------------------------------------------------------------------
template <int CIN, int COUT, int HO, int WO, int BN, int SK>
__global__ __launch_bounds__(256) void kan_gemm(
    const float* __restrict__ in, const float* __restrict__ bw,
    const float* __restrict__ sw, const float* __restrict__ ss,
    float* __restrict__ outp) {
  constexpr int BM = 64, TM = 4, TN = 4, FC = 16;
  constexpr int F = CIN * 9;
  constexpr int HI = HO / 2, WI = WO / 2;
  constexpr int M = BATCH * HO * WO;
  constexpr int FPB = F / SK;

  __shared__ float Ae[FC * 9][BM];

  const int t = threadIdx.x;
  const int mbase = blockIdx.x * BM;
  const int obase = blockIdx.y * BN;
  const int f0 = blockIdx.z * FPB;

  const int cg = t & (BN / TN - 1);
  const int rg = t / (BN / TN);
  const int m0 = rg * TM;
  const int o0 = obase + cg * TN;

  float acc[TM][TN] = {};

  for (int fc = f0; fc < f0 + FPB; fc += FC) {
#pragma unroll
    for (int j = 0; j < BM * FC / 256; ++j) {
      int p = j * 256 + t;
      int ml = p & (BM - 1);
      int df = p >> 6;
      int f = fc + df;
      int c = f / 9;
      int r = f - c * 9;
      int kh = r / 3, kw = r - kh * 3;
      int m = mbase + ml;
      int bb = m / (HO * WO);
      int rem = m % (HO * WO);
      int hh = rem / WO, ww = rem % WO;
      int hp = hh + kh - 1, wp = ww + kw - 1;
      float val = 0.f;
      if (hp >= 0 && hp < HO && wp >= 0 && wp < WO)
        val = in[((bb * CIN + c) * HI + (hp >> 1)) * WI + (wp >> 1)];
      float e[9];
      expand9(val, e);
#pragma unroll
      for (int v = 0; v < 9; ++v) Ae[df * 9 + v][ml] = e[v];
    }
    __syncthreads();

#pragma unroll 2
    for (int df = 0; df < FC; ++df) {
      int f = fc + df;
      float wb[TN], wsv[TN][8];
#pragma unroll
      for (int tn = 0; tn < TN; ++tn) {
        int i = (o0 + tn) * F + f;
        wb[tn] = bw[i];
        float sc = ss[i];
        const float4* sp = reinterpret_cast<const float4*>(sw + (size_t)i * 8);
        float4 s0 = sp[0], s1 = sp[1];
        wsv[tn][0] = s0.x * sc; wsv[tn][1] = s0.y * sc;
        wsv[tn][2] = s0.z * sc; wsv[tn][3] = s0.w * sc;
        wsv[tn][4] = s1.x * sc; wsv[tn][5] = s1.y * sc;
        wsv[tn][6] = s1.z * sc; wsv[tn][7] = s1.w * sc;
      }
      float a[9][TM];
#pragma unroll
      for (int v = 0; v < 9; ++v) {
        float4 q = *reinterpret_cast<const float4*>(&Ae[df * 9 + v][m0]);
        a[v][0] = q.x; a[v][1] = q.y; a[v][2] = q.z; a[v][3] = q.w;
      }
#pragma unroll
      for (int tm = 0; tm < TM; ++tm)
#pragma unroll
        for (int tn = 0; tn < TN; ++tn) acc[tm][tn] += a[0][tm] * wb[tn];
#pragma unroll
      for (int v = 1; v < 9; ++v)
#pragma unroll
        for (int tm = 0; tm < TM; ++tm)
#pragma unroll
          for (int tn = 0; tn < TN; ++tn)
            acc[tm][tn] += a[v][tm] * wsv[tn][v - 1];
    }
    __syncthreads();
  }

  if constexpr (SK > 1) {
    float* p = outp + (size_t)blockIdx.z * M * COUT;
#pragma unroll
    for (int tm = 0; tm < TM; ++tm) {
      int m = mbase + m0 + tm;
#pragma unroll
      for (int tn = 0; tn < TN; ++tn)
        p[(size_t)m * COUT + (o0 + tn)] = acc[tm][tn];
    }
  } else {
#pragma unroll
    for (int tm = 0; tm < TM; ++tm) {
      int m = mbase + m0 + tm;
      int bb = m / (HO * WO);
      int rem = m % (HO * WO);
      int hh = rem / WO, ww = rem % WO;
#pragma unroll
      for (int tn = 0; tn < TN; ++tn) {
        int o = o0 + tn;
        outp[((bb * COUT + o) * HO + hh) * WO + ww] = acc[tm][tn];
      }
    }
  }
}

template <int COUT, int HO, int WO, int SK>
__global__ __launch_bounds__(256) void reduce_partials_old(
    const float* __restrict__ part, float* __restrict__ act) {
  constexpr int M = BATCH * HO * WO;
  int idx = blockIdx.x * 256 + threadIdx.x;
  if (idx >= M * COUT) return;
  float s = 0.f;
#pragma unroll
  for (int k = 0; k < SK; ++k) s += part[(size_t)k * M * COUT + idx];
  int m = idx / COUT, o = idx - (idx / COUT) * COUT;
  int bb = m / (HO * WO);
  int rem = m % (HO * WO);
  int hh = rem / WO, ww = rem % WO;
  act[((bb * COUT + o) * HO + hh) * WO + ww] = s;
}

__global__ __launch_bounds__(256) void kan_l4_split(
    const float* __restrict__ a3, const float* __restrict__ bw,
    const float* __restrict__ sw, const float* __restrict__ ss,
    float* __restrict__ p4) {
  int tid = blockIdx.x * 256 + threadIdx.x;
  int cs = tid >> 16, pix = tid & 65535;
  int b = pix >> 10, rem = pix & 1023, h = rem >> 5, w = rem & 31;
  float acc[3] = {0.f, 0.f, 0.f};
  for (int c = cs * 16; c < cs * 16 + 16; ++c) {
#pragma unroll
    for (int kh = 0; kh < 3; ++kh) {
#pragma unroll
      for (int kw = 0; kw < 3; ++kw) {
        int f = (c * 3 + kh) * 3 + kw;
        int hp = h + kh - 1, wp = w + kw - 1;
        float x = 0.f;
        if ((unsigned)hp < 32u && (unsigned)wp < 32u)
          x = a3[((b * 64 + c) * 16 + (hp >> 1)) * 16 + (wp >> 1)];
        float e[9];
        expand9(x, e);
#pragma unroll
        for (int o = 0; o < 3; ++o) {
          int i = o * 576 + f;
          float d = e[1] * sw[i * 8 + 0];
#pragma unroll
          for (int v = 1; v < 8; ++v) d += e[v + 1] * sw[i * 8 + v];
          acc[o] += e[0] * bw[i] + d * ss[i];
        }
      }
    }
  }
#pragma unroll
  for (int o = 0; o < 3; ++o)
    p4[cs * 196608 + ((b * 3 + o) << 10) + (h << 5) + w] = acc[o];
}

__global__ __launch_bounds__(256) void reduce_tanh_l4(
    const float* __restrict__ p4, float* __restrict__ out) {
  int i = blockIdx.x * 256 + threadIdx.x;
  float s = p4[i] + p4[i + 196608] + p4[i + 2 * 196608] + p4[i + 3 * 196608];
  out[i] = tanhf(s);
}

// ---------------------------------------------------------------------------
template <int SK1, int SK2, int SK3>
static void run_main(const float* h, float* a1, float* a2, float* a3,
                     float* part, float* bexp,
                     const float* bw1, const float* sw1, const float* ss1,
                     const float* bw2, const float* sw2, const float* ss2,
                     const float* bw3, const float* sw3, const float* ss3,
                     hipStream_t stream) {
  prep_bexp_t<4608, 256><<<2304, 256, 0, stream>>>(bw1, sw1, ss1, bexp);
  gemm_exp<512, 256, 4, 4, 128, 128, SK1>
      <<<dim3(8, 2, SK1), 256, 0, stream>>>(h, bexp, part);
  reduce_p<256, 4, 4><<<1024, 256, 0, stream>>>(part, a1, SK1);

  prep_bexp_t<2304, 128><<<576, 256, 0, stream>>>(bw2, sw2, ss2, bexp);
  gemm_exp<256, 128, 8, 8, 128, 128, SK2>
      <<<dim3(32, 1, SK2), 256, 0, stream>>>(a1, bexp, part);
  reduce_p<128, 8, 8><<<2048, 256, 0, stream>>>(part, a2, SK2);

  prep_bexp_t<1152, 64><<<144, 256, 0, stream>>>(bw3, sw3, ss3, bexp);
  gemm_exp<128, 64, 16, 16, 256, 64, SK3>
      <<<dim3(64, 1, SK3), 256, 0, stream>>>(a2, bexp, part);
  reduce_p<64, 16, 16><<<4096, 256, 0, stream>>>(part, a3, SK3);
}

extern "C" void kernel_launch(void* const* d_in, const int* in_sizes, int n_in,
                              void* d_out, int out_size, void* d_ws,
                              size_t ws_size, hipStream_t stream) {
  const float* x     = (const float*)d_in[0];
  const float* lin_w = (const float*)d_in[1];
  const float* lin_b = (const float*)d_in[2];
  const float* bw1 = (const float*)d_in[3];
  const float* sw1 = (const float*)d_in[4];
  const float* ss1 = (const float*)d_in[5];
  const float* bw2 = (const float*)d_in[6];
  const float* sw2 = (const float*)d_in[7];
  const float* ss2 = (const float*)d_in[8];
  const float* bw3 = (const float*)d_in[9];
  const float* sw3 = (const float*)d_in[10];
  const float* ss3 = (const float*)d_in[11];
  const float* bw4 = (const float*)d_in[12];
  const float* sw4 = (const float*)d_in[13];
  const float* ss4 = (const float*)d_in[14];

  float* wsf = (float*)d_ws;
  float* h  = wsf;                 // 131072
  float* a1 = h + 131072;          // 262144
  float* a2 = a1 + 262144;         // 524288
  float* a3 = a2 + 524288;         // 1048576
  float* bexp = a3 + 1048576;      // 10616832 (L1 Bexp, largest)
  float* part = bexp + 10616832;   // SK partials
  float* E    = bexp;              // L4 expansion aliases bexp+part (12.6M)
  float* wl4  = h;                 // L4 fused weights alias h (dead after L1)
  const size_t baseFloats = 1966080 + 10616832;
  size_t availFloats = ws_size / 4 > baseFloats ? ws_size / 4 - baseFloats : 0;

  linear_relu_kernel<<<512, 256, 0, stream>>>(x, lin_w, lin_b, h);

  bool mainPath = true;
  if (availFloats >= 8388608) {
    run_main<32, 16, 8>(h, a1, a2, a3, part, bexp, bw1, sw1, ss1, bw2, sw2,
                        ss2, bw3, sw3, ss3, stream);
  } else if (availFloats >= 4194304) {
    run_main<16, 8, 4>(h, a1, a2, a3, part, bexp, bw1, sw1, ss1, bw2, sw2,
                       ss2, bw3, sw3, ss3, stream);
  } else if (availFloats >= 2097152) {
    run_main<8, 4, 2>(h, a1, a2, a3, part, bexp, bw1, sw1, ss1, bw2, sw2,
                      ss2, bw3, sw3, ss3, stream);
  } else {
    mainPath = false;
    float* partOld = a3 + 1048576;
    kan_gemm<512, 256, 4, 4, 64, 8>
        <<<dim3(16, 4, 8), 256, 0, stream>>>(h, bw1, sw1, ss1, partOld);
    reduce_partials_old<256, 4, 4, 8><<<1024, 256, 0, stream>>>(partOld, a1);
    kan_gemm<256, 128, 8, 8, 64, 2>
        <<<dim3(64, 2, 2), 256, 0, stream>>>(a1, bw2, sw2, ss2, partOld);
    reduce_partials_old<128, 8, 8, 2><<<2048, 256, 0, stream>>>(partOld, a2);
    kan_gemm<128, 64, 16, 16, 64, 1>
        <<<dim3(256, 1, 1), 256, 0, stream>>>(a2, bw3, sw3, ss3, a3);
  }

  if (mainPath) {
    prep_wl4<<<61, 256, 0, stream>>>(bw4, sw4, ss4, wl4);
    l4_expand<<<4096, 256, 0, stream>>>(a3, E);
    kan_l4_v2<<<256, 256, 0, stream>>>(E, wl4, (float*)d_out);
  } else {
    float* partOld = a3 + 1048576;
    kan_l4_split<<<1024, 256, 0, stream>>>(a3, bw4, sw4, ss4, partOld);
    reduce_tanh_l4<<<768, 256, 0, stream>>>(partOld, (float*)d_out);
  }
}

// Round 6
// 620.918 us; speedup vs baseline: 8.9184x; 2.3409x over previous
//
#include <hip/hip_runtime.h>
#include <cstdint>
#include <cmath>

#define BATCH 64

typedef __attribute__((ext_vector_type(8))) __bf16 bf16x8;
typedef __attribute__((ext_vector_type(16))) float f32x16;

// ---------------------------------------------------------------------------
// Spline + silu expansion: x -> [silu(x), B_0(x) .. B_7(x)]
// ---------------------------------------------------------------------------
__device__ __forceinline__ void expand9(float x, float* e) {
  float t = __expf(-x);
  e[0] = __fdividef(x, 1.f + t);  // silu
  float b[11];
#pragma unroll
  for (int j = 0; j < 11; ++j) {
    float gj  = 0.4f * (float)j - 2.2f;
    float gj1 = 0.4f * (float)(j + 1) - 2.2f;
    b[j] = (x >= gj && x < gj1) ? 1.f : 0.f;
  }
#pragma unroll
  for (int k = 1; k <= 3; ++k) {
    float inv = 1.f / (0.4f * (float)k);
#pragma unroll
    for (int j = 0; j < 11 - k; ++j) {
      float gj   = 0.4f * (float)j - 2.2f;
      float gjk1 = 0.4f * (float)(j + k + 1) - 2.2f;
      b[j] = ((x - gj) * b[j] + (gjk1 - x) * b[j + 1]) * inv;
    }
  }
#pragma unroll
  for (int v = 0; v < 8; ++v) e[v + 1] = b[v];
}

// bf16 split helpers (round-to-nearest-even)
__device__ __forceinline__ unsigned short f2bf(float x) {
  uint32_t u = __float_as_uint(x);
  uint32_t r = u + 0x7fffu + ((u >> 16) & 1u);
  return (unsigned short)(r >> 16);
}
__device__ __forceinline__ float bf2f(unsigned short h) {
  return __uint_as_float(((uint32_t)h) << 16);
}
__device__ __forceinline__ uint32_t packsplit(float x) {
  unsigned short hi = f2bf(x);
  unsigned short lo = f2bf(x - bf2f(hi));
  return (uint32_t)hi | ((uint32_t)lo << 16);
}

// ---------------------------------------------------------------------------
// h = relu(x @ lin_w^T + lin_b); also writes packed expansion E (main path)
// ---------------------------------------------------------------------------
__global__ __launch_bounds__(256) void linear_pack_kernel(
    const float* __restrict__ x, const float* __restrict__ w,
    const float* __restrict__ bias, float* __restrict__ h,
    uint32_t* __restrict__ E, int writeE) {
  int idx = blockIdx.x * 256 + threadIdx.x;  // 64*2048
  int b = idx >> 11, o = idx & 2047;
  const float* xr = x + b * 100;
  const float* wr = w + o * 100;
  float acc = bias[o];
#pragma unroll 4
  for (int k = 0; k < 100; ++k) acc += xr[k] * wr[k];
  float hv = fmaxf(acc, 0.f);
  h[idx] = hv;
  if (writeE) {
    float e[9];
    expand9(hv, e);
    uint32_t* p = E + (size_t)idx * 9;
#pragma unroll
    for (int v = 0; v < 9; ++v) p[v] = packsplit(e[v]);
  }
}

// ---------------------------------------------------------------------------
// Pack expanded weights into MFMA-staging layout:
// Bg[kc][plane(hi=0,lo=1)][v(9)][n(N)][fl(16)]  (bf16)
// where f = kc*16+fl,  w = v==0 ? bw[n,f] : sw[n,f,v-1]*ss[n,f]
// ---------------------------------------------------------------------------
template <int F, int N>
__global__ __launch_bounds__(256) void prep_bpack(
    const float* __restrict__ bw, const float* __restrict__ sw,
    const float* __restrict__ ss, unsigned short* __restrict__ Bg) {
  int idx = blockIdx.x * 256 + threadIdx.x;  // over (F/16)*9*N*16
  int fl = idx & 15;
  int n = (idx >> 4) & (N - 1);
  int rest = idx >> 4;
  rest /= N;
  int v = rest % 9;
  int kc = rest / 9;
  int f = kc * 16 + fl;
  size_t src = (size_t)n * F + f;
  float wv = (v == 0) ? bw[src] : sw[src * 8 + (v - 1)] * ss[src];
  unsigned short hi = f2bf(wv);
  unsigned short lo = f2bf(wv - bf2f(hi));
  size_t base = ((size_t)kc * 2 * 9 + v) * N * 16 + (size_t)n * 16 + fl;
  Bg[base] = hi;                          // plane 0
  Bg[base + (size_t)9 * N * 16] = lo;     // plane 1
}

// ---------------------------------------------------------------------------
// Split-bf16 MFMA GEMM over expanded basis.
// C[M, N] = sum_{f,v} basis_v(x[m,f]) * W[n,f,v],  K v-major in 16-f chunks.
// Block: 64m x 64n, 4 waves (2x2), wave-tile 32x32, mfma_f32_32x32x16_bf16.
// A from packed E (gather+split into LDS), B linear-copied from Bg.
// Writes split-K partials part[z][M][N].
// ---------------------------------------------------------------------------
template <int CIN, int COUT, int HO, int WO, int SK>
__global__ __launch_bounds__(256, 2) void gemm_mfma(
    const uint32_t* __restrict__ E, const unsigned short* __restrict__ Bg,
    float* __restrict__ part) {
  constexpr int F = CIN * 9;
  constexpr int NKC = F / 16;
  constexpr int HI = HO / 2, WI = WO / 2;
  constexpr int M = BATCH * HO * WO;
  constexpr int CPB = NKC / SK;  // 36
  static_assert(NKC % SK == 0, "sk");

  // 4 planes of [9][64][16] bf16: A_hi, A_lo, B_hi, B_lo
  __shared__ __align__(16) unsigned short lds[4 * 9216];

  const int t = threadIdx.x;
  const int mbase = blockIdx.x * 64;
  const int nb = blockIdx.y;
  const int kc0 = blockIdx.z * CPB;

  // expansion of padded zero, packed
  uint32_t ez[9];
  {
    float e0[9];
    expand9(0.f, e0);
#pragma unroll
    for (int v = 0; v < 9; ++v) ez[v] = packsplit(e0[v]);
  }

  const int lane = t & 63, wv_ = t >> 6;
  const int wm = wv_ >> 1, wn = wv_ & 1;
  const int frow = lane & 31, fkg = lane >> 5;
  const int aoff = ((wm * 32 + frow) * 16 + fkg * 8) * 2;  // bytes
  const int boff = ((wn * 32 + frow) * 16 + fkg * 8) * 2;

  f32x16 acc;
#pragma unroll
  for (int i = 0; i < 16; ++i) acc[i] = 0.f;

  for (int ci = 0; ci < CPB; ++ci) {
    const int kc = kc0 + ci;
    __syncthreads();

    // ---- stage A: 64 m x 16 fl ----
#pragma unroll
    for (int i = 0; i < 4; ++i) {
      int task = i * 256 + t;
      int ml = task >> 4, fl = task & 15;
      int f = kc * 16 + fl;
      int c = f / 9, r = f - 9 * c;
      int kh = r / 3, kw = r - kh * 3;
      int m = mbase + ml;
      int b = m / (HO * WO), hw2 = m % (HO * WO);
      int hh = hw2 / WO, ww = hw2 % WO;
      int hp = hh + kh - 1, wp = ww + kw - 1;
      bool ok = (unsigned)hp < (unsigned)HO && (unsigned)wp < (unsigned)WO;
      uint32_t uv[9];
      if (ok) {
        const uint32_t* ep =
            E + (size_t)(((b * CIN + c) * HI + (hp >> 1)) * WI + (wp >> 1)) * 9;
#pragma unroll
        for (int v = 0; v < 9; ++v) uv[v] = ep[v];
      } else {
#pragma unroll
        for (int v = 0; v < 9; ++v) uv[v] = ez[v];
      }
      int base = ml * 16 + fl;
#pragma unroll
      for (int v = 0; v < 9; ++v) {
        lds[v * 1024 + base] = (unsigned short)(uv[v] & 0xffffu);
        lds[9216 + v * 1024 + base] = (unsigned short)(uv[v] >> 16);
      }
    }

    // ---- stage B: linear copy of 36.9 KB chunk (16B units) ----
    {
      const unsigned short* bsrc = Bg + (size_t)kc * (2 * 9 * COUT * 16);
#pragma unroll
      for (int g = 0; g < 9; ++g) {
        int u = g * 256 + t;  // 0..2303
        int pl = (u >= 1152) ? 1 : 0;
        int rr = u - pl * 1152;
        int v = rr >> 7, q = rr & 127;
        int nl = q >> 1, half = q & 1;
        size_t srcE = (size_t)pl * (9 * COUT * 16) + (size_t)v * (COUT * 16) +
                      (size_t)(nb * 64 + nl) * 16 + half * 8;
        int dst = (2 + pl) * 9216 + v * 1024 + nl * 16 + half * 8;
        *reinterpret_cast<float4*>(&lds[dst]) =
            *reinterpret_cast<const float4*>(&bsrc[srcE]);
      }
    }
    __syncthreads();

    // ---- compute: 9 v-steps x 3 split-products ----
#pragma unroll
    for (int v = 0; v < 9; ++v) {
      const char* lb = reinterpret_cast<const char*>(lds);
      bf16x8 ah = *reinterpret_cast<const bf16x8*>(lb + v * 2048 + aoff);
      bf16x8 al = *reinterpret_cast<const bf16x8*>(lb + 18432 + v * 2048 + aoff);
      bf16x8 bh = *reinterpret_cast<const bf16x8*>(lb + 36864 + v * 2048 + boff);
      bf16x8 bl = *reinterpret_cast<const bf16x8*>(lb + 55296 + v * 2048 + boff);
      acc = __builtin_amdgcn_mfma_f32_32x32x16_bf16(ah, bh, acc, 0, 0, 0);
      acc = __builtin_amdgcn_mfma_f32_32x32x16_bf16(ah, bl, acc, 0, 0, 0);
      acc = __builtin_amdgcn_mfma_f32_32x32x16_bf16(al, bh, acc, 0, 0, 0);
    }
  }

  // ---- epilogue: C/D layout col=lane&31, row=(reg&3)+8*(reg>>2)+4*(lane>>5)
  float* p = part + (size_t)blockIdx.z * M * COUT;
  const int gn = nb * 64 + wn * 32 + frow;
#pragma unroll
  for (int r = 0; r < 16; ++r) {
    int mlocal = (r & 3) + 8 * (r >> 2) + 4 * fkg;
    int gm = mbase + wm * 32 + mlocal;
    p[(size_t)gm * COUT + gn] = acc[r];
  }
}

// ---------------------------------------------------------------------------
// Reduce split-K partials -> activation value; write packed expansion E
// (feeds the next gemm_mfma layer).
// ---------------------------------------------------------------------------
template <int COUT, int HO, int WO>
__global__ __launch_bounds__(256) void reduce_pe_pack(
    const float* __restrict__ part, uint32_t* __restrict__ E, int SK) {
  constexpr int M = BATCH * HO * WO;
  int idx = blockIdx.x * 256 + threadIdx.x;  // act-layout index
  int ww = idx % WO;
  int tmp = idx / WO;
  int hh = tmp % HO;
  tmp /= HO;
  int o = tmp % COUT;
  int b = tmp / COUT;
  int m = (b * HO + hh) * WO + ww;
  float s = 0.f;
  for (int k = 0; k < SK; ++k) s += part[((size_t)k * M + m) * COUT + o];
  float e[9];
  expand9(s, e);
  uint32_t* p = E + (size_t)idx * 9;
#pragma unroll
  for (int v = 0; v < 9; ++v) p[v] = packsplit(e[v]);
}

// plain reduce (L3 -> a3 for the L4 pipeline)
template <int COUT, int HO, int WO>
__global__ __launch_bounds__(256) void reduce_p(
    const float* __restrict__ part, float* __restrict__ act, int SK) {
  constexpr int M = BATCH * HO * WO;
  int idx = blockIdx.x * 256 + threadIdx.x;
  int ww = idx % WO;
  int tmp = idx / WO;
  int hh = tmp % HO;
  tmp /= HO;
  int o = tmp % COUT;
  int b = tmp / COUT;
  int m = (b * HO + hh) * WO + ww;
  float s = 0.f;
  for (int k = 0; k < SK; ++k) s += part[((size_t)k * M + m) * COUT + o];
  act[idx] = s;
}

// ---------------------------------------------------------------------------
// L4: precomputed expansion E[b][c][16][16][12] fp32 + fused-weight consumer,
// split 4-way over channels + tanh-reduce.
// ---------------------------------------------------------------------------
__global__ __launch_bounds__(256) void l4_expand(
    const float* __restrict__ a3, float* __restrict__ E) {
  int idx = blockIdx.x * 256 + threadIdx.x;  // 64*64*256
  float x = a3[idx];
  float e[9];
  expand9(x, e);
  float4* p = reinterpret_cast<float4*>(E + (size_t)idx * 12);
  p[0] = make_float4(e[0], e[1], e[2], e[3]);
  p[1] = make_float4(e[4], e[5], e[6], e[7]);
  p[2] = make_float4(e[8], 0.f, 0.f, 0.f);
}

__global__ __launch_bounds__(256) void prep_wl4(
    const float* __restrict__ bw, const float* __restrict__ sw,
    const float* __restrict__ ss, float* __restrict__ W) {
  int idx = blockIdx.x * 256 + threadIdx.x;  // 576*9*3 = 15552
  if (idx >= 15552) return;
  int o = idx % 3;
  int rest = idx / 3;
  int v = rest % 9;
  int f = rest / 9;
  float w = (v == 0) ? bw[o * 576 + f]
                     : sw[((size_t)(o * 576 + f)) * 8 + (v - 1)] * ss[o * 576 + f];
  W[idx] = w;
}

__device__ __forceinline__ void l4_load(const float* __restrict__ base,
                                        const float* __restrict__ ez,
                                        int gi0, int gj0, bool vr0, bool vr1,
                                        bool vc0, bool vc1, float e[2][2][12]) {
#pragma unroll
  for (int a = 0; a < 2; ++a)
#pragma unroll
    for (int b2 = 0; b2 < 2; ++b2) {
      bool ok = (a ? vr1 : vr0) && (b2 ? vc1 : vc0);
      if (ok) {
        const float4* p = reinterpret_cast<const float4*>(
            base + ((gi0 + a) * 16 + (gj0 + b2)) * 12);
        float4 q0 = p[0], q1 = p[1], q2 = p[2];
        e[a][b2][0] = q0.x; e[a][b2][1] = q0.y; e[a][b2][2] = q0.z;
        e[a][b2][3] = q0.w; e[a][b2][4] = q1.x; e[a][b2][5] = q1.y;
        e[a][b2][6] = q1.z; e[a][b2][7] = q1.w; e[a][b2][8] = q2.x;
      } else {
#pragma unroll
        for (int v = 0; v < 9; ++v) e[a][b2][v] = ez[v];
      }
    }
}

template <int PH, int PW>
__device__ __forceinline__ void l4_compute(const float e[2][2][12],
                                           const float* __restrict__ wc,
                                           float acc[3]) {
#pragma unroll
  for (int kh = 0; kh < 3; ++kh) {
    const int sh = (kh > PH) ? 1 : 0;
#pragma unroll
    for (int kw = 0; kw < 3; ++kw) {
      const int sw_ = (kw > PW) ? 1 : 0;
      const float* wp = wc + (kh * 3 + kw) * 27;
#pragma unroll
      for (int v = 0; v < 9; ++v) {
        float ev = e[sh][sw_][v];
        acc[0] = fmaf(ev, wp[v * 3 + 0], acc[0]);
        acc[1] = fmaf(ev, wp[v * 3 + 1], acc[1]);
        acc[2] = fmaf(ev, wp[v * 3 + 2], acc[2]);
      }
    }
  }
}

template <int PH, int PW>
__device__ __forceinline__ void l4_acc(const float* __restrict__ E,
                                       const float* __restrict__ W,
                                       const float* __restrict__ ez, int bb,
                                       int c0, int gi0, int gj0, float acc[3]) {
  const bool vr0 = (unsigned)gi0 < 16u, vr1 = (unsigned)(gi0 + 1) < 16u;
  const bool vc0 = (unsigned)gj0 < 16u, vc1 = (unsigned)(gj0 + 1) < 16u;
  const float* base0 = E + (size_t)bb * 64 * 3072;
  float eA[2][2][12], eB[2][2][12];
  l4_load(base0 + c0 * 3072, ez, gi0, gj0, vr0, vr1, vc0, vc1, eA);
  for (int c = c0; c < c0 + 16; c += 2) {
    l4_load(base0 + (c + 1) * 3072, ez, gi0, gj0, vr0, vr1, vc0, vc1, eB);
    l4_compute<PH, PW>(eA, W + c * 243, acc);
    if (c + 2 < c0 + 16)
      l4_load(base0 + (c + 2) * 3072, ez, gi0, gj0, vr0, vr1, vc0, vc1, eA);
    l4_compute<PH, PW>(eB, W + (c + 1) * 243, acc);
  }
}

__global__ __launch_bounds__(256) void kan_l4_v3(
    const float* __restrict__ E, const float* __restrict__ W,
    float* __restrict__ p4) {
  const int bid = blockIdx.x;            // 64 bb * 4 tile * 4 cs
  const int bb = bid >> 4, tile = (bid >> 2) & 3, cs = bid & 3;
  const int th = tile >> 1, tw = tile & 1;
  const int t = threadIdx.x, wave = t >> 6, lane = t & 63;
  const int i = lane >> 3, j = lane & 7;
  const int ph = wave >> 1, pw = wave & 1;
  const int h = th * 16 + 2 * i + ph, w = tw * 16 + 2 * j + pw;
  const int gi0 = th * 8 + i + ph - 1, gj0 = tw * 8 + j + pw - 1;
  float ez[9];
  expand9(0.f, ez);
  float acc[3] = {0.f, 0.f, 0.f};
  const int c0 = cs * 16;
  if (wave == 0)
    l4_acc<0, 0>(E, W, ez, bb, c0, gi0, gj0, acc);
  else if (wave == 1)
    l4_acc<0, 1>(E, W, ez, bb, c0, gi0, gj0, acc);
  else if (wave == 2)
    l4_acc<1, 0>(E, W, ez, bb, c0, gi0, gj0, acc);
  else
    l4_acc<1, 1>(E, W, ez, bb, c0, gi0, gj0, acc);
#pragma unroll
  for (int o = 0; o < 3; ++o)
    p4[cs * 196608 + ((bb * 3 + o) << 10) + (h << 5) + w] = acc[o];
}

__global__ __launch_bounds__(256) void reduce_tanh_l4(
    const float* __restrict__ p4, float* __restrict__ out) {
  int i = blockIdx.x * 256 + threadIdx.x;  // 196608
  float s = p4[i] + p4[i + 196608] + p4[i + 2 * 196608] + p4[i + 3 * 196608];
  out[i] = tanhf(s);
}

// ---------------------------------------------------------------------------
// Fallback path (round-1 proven) for small workspace
// ---------------------------------------------------------------------------
template <int CIN, int COUT, int HO, int WO, int BN, int SK>
__global__ __launch_bounds__(256) void kan_gemm(
    const float* __restrict__ in, const float* __restrict__ bw,
    const float* __restrict__ sw, const float* __restrict__ ss,
    float* __restrict__ outp) {
  constexpr int BM = 64, TM = 4, TN = 4, FC = 16;
  constexpr int F = CIN * 9;
  constexpr int HI = HO / 2, WI = WO / 2;
  constexpr int M = BATCH * HO * WO;
  constexpr int FPB = F / SK;

  __shared__ float Ae[FC * 9][BM];

  const int t = threadIdx.x;
  const int mbase = blockIdx.x * BM;
  const int obase = blockIdx.y * BN;
  const int f0 = blockIdx.z * FPB;

  const int cg = t & (BN / TN - 1);
  const int rg = t / (BN / TN);
  const int m0 = rg * TM;
  const int o0 = obase + cg * TN;

  float acc[TM][TN] = {};

  for (int fc = f0; fc < f0 + FPB; fc += FC) {
#pragma unroll
    for (int j = 0; j < BM * FC / 256; ++j) {
      int p = j * 256 + t;
      int ml = p & (BM - 1);
      int df = p >> 6;
      int f = fc + df;
      int c = f / 9;
      int r = f - c * 9;
      int kh = r / 3, kw = r - kh * 3;
      int m = mbase + ml;
      int bb = m / (HO * WO);
      int rem = m % (HO * WO);
      int hh = rem / WO, ww = rem % WO;
      int hp = hh + kh - 1, wp = ww + kw - 1;
      float val = 0.f;
      if (hp >= 0 && hp < HO && wp >= 0 && wp < WO)
        val = in[((bb * CIN + c) * HI + (hp >> 1)) * WI + (wp >> 1)];
      float e[9];
      expand9(val, e);
#pragma unroll
      for (int v = 0; v < 9; ++v) Ae[df * 9 + v][ml] = e[v];
    }
    __syncthreads();

#pragma unroll 2
    for (int df = 0; df < FC; ++df) {
      int f = fc + df;
      float wb[TN], wsv[TN][8];
#pragma unroll
      for (int tn = 0; tn < TN; ++tn) {
        int i = (o0 + tn) * F + f;
        wb[tn] = bw[i];
        float sc = ss[i];
        const float4* sp = reinterpret_cast<const float4*>(sw + (size_t)i * 8);
        float4 s0 = sp[0], s1 = sp[1];
        wsv[tn][0] = s0.x * sc; wsv[tn][1] = s0.y * sc;
        wsv[tn][2] = s0.z * sc; wsv[tn][3] = s0.w * sc;
        wsv[tn][4] = s1.x * sc; wsv[tn][5] = s1.y * sc;
        wsv[tn][6] = s1.z * sc; wsv[tn][7] = s1.w * sc;
      }
      float a[9][TM];
#pragma unroll
      for (int v = 0; v < 9; ++v) {
        float4 q = *reinterpret_cast<const float4*>(&Ae[df * 9 + v][m0]);
        a[v][0] = q.x; a[v][1] = q.y; a[v][2] = q.z; a[v][3] = q.w;
      }
#pragma unroll
      for (int tm = 0; tm < TM; ++tm)
#pragma unroll
        for (int tn = 0; tn < TN; ++tn) acc[tm][tn] += a[0][tm] * wb[tn];
#pragma unroll
      for (int v = 1; v < 9; ++v)
#pragma unroll
        for (int tm = 0; tm < TM; ++tm)
#pragma unroll
          for (int tn = 0; tn < TN; ++tn)
            acc[tm][tn] += a[v][tm] * wsv[tn][v - 1];
    }
    __syncthreads();
  }

  if constexpr (SK > 1) {
    float* p = outp + (size_t)blockIdx.z * M * COUT;
#pragma unroll
    for (int tm = 0; tm < TM; ++tm) {
      int m = mbase + m0 + tm;
#pragma unroll
      for (int tn = 0; tn < TN; ++tn)
        p[(size_t)m * COUT + (o0 + tn)] = acc[tm][tn];
    }
  } else {
#pragma unroll
    for (int tm = 0; tm < TM; ++tm) {
      int m = mbase + m0 + tm;
      int bb = m / (HO * WO);
      int rem = m % (HO * WO);
      int hh = rem / WO, ww = rem % WO;
#pragma unroll
      for (int tn = 0; tn < TN; ++tn) {
        int o = o0 + tn;
        outp[((bb * COUT + o) * HO + hh) * WO + ww] = acc[tm][tn];
      }
    }
  }
}

template <int COUT, int HO, int WO, int SK>
__global__ __launch_bounds__(256) void reduce_partials_old(
    const float* __restrict__ part, float* __restrict__ act) {
  constexpr int M = BATCH * HO * WO;
  int idx = blockIdx.x * 256 + threadIdx.x;
  if (idx >= M * COUT) return;
  float s = 0.f;
#pragma unroll
  for (int k = 0; k < SK; ++k) s += part[(size_t)k * M * COUT + idx];
  int m = idx / COUT, o = idx - (idx / COUT) * COUT;
  int bb = m / (HO * WO);
  int rem = m % (HO * WO);
  int hh = rem / WO, ww = rem % WO;
  act[((bb * COUT + o) * HO + hh) * WO + ww] = s;
}

__global__ __launch_bounds__(256) void kan_l4_split(
    const float* __restrict__ a3, const float* __restrict__ bw,
    const float* __restrict__ sw, const float* __restrict__ ss,
    float* __restrict__ p4) {
  int tid = blockIdx.x * 256 + threadIdx.x;
  int cs = tid >> 16, pix = tid & 65535;
  int b = pix >> 10, rem = pix & 1023, h = rem >> 5, w = rem & 31;
  float acc[3] = {0.f, 0.f, 0.f};
  for (int c = cs * 16; c < cs * 16 + 16; ++c) {
#pragma unroll
    for (int kh = 0; kh < 3; ++kh) {
#pragma unroll
      for (int kw = 0; kw < 3; ++kw) {
        int f = (c * 3 + kh) * 3 + kw;
        int hp = h + kh - 1, wp = w + kw - 1;
        float x = 0.f;
        if ((unsigned)hp < 32u && (unsigned)wp < 32u)
          x = a3[((b * 64 + c) * 16 + (hp >> 1)) * 16 + (wp >> 1)];
        float e[9];
        expand9(x, e);
#pragma unroll
        for (int o = 0; o < 3; ++o) {
          int i = o * 576 + f;
          float d = e[1] * sw[i * 8 + 0];
#pragma unroll
          for (int v = 1; v < 8; ++v) d += e[v + 1] * sw[i * 8 + v];
          acc[o] += e[0] * bw[i] + d * ss[i];
        }
      }
    }
  }
#pragma unroll
  for (int o = 0; o < 3; ++o)
    p4[cs * 196608 + ((b * 3 + o) << 10) + (h << 5) + w] = acc[o];
}

// ---------------------------------------------------------------------------
extern "C" void kernel_launch(void* const* d_in, const int* in_sizes, int n_in,
                              void* d_out, int out_size, void* d_ws,
                              size_t ws_size, hipStream_t stream) {
  const float* x     = (const float*)d_in[0];
  const float* lin_w = (const float*)d_in[1];
  const float* lin_b = (const float*)d_in[2];
  const float* bw1 = (const float*)d_in[3];
  const float* sw1 = (const float*)d_in[4];
  const float* ss1 = (const float*)d_in[5];
  const float* bw2 = (const float*)d_in[6];
  const float* sw2 = (const float*)d_in[7];
  const float* ss2 = (const float*)d_in[8];
  const float* bw3 = (const float*)d_in[9];
  const float* sw3 = (const float*)d_in[10];
  const float* ss3 = (const float*)d_in[11];
  const float* bw4 = (const float*)d_in[12];
  const float* sw4 = (const float*)d_in[13];
  const float* ss4 = (const float*)d_in[14];

  float* wsf = (float*)d_ws;
  float* h  = wsf;                        // 131072
  float* a1 = h + 131072;                 // 262144 (fallback only)
  float* a2 = a1 + 262144;                // 524288 (fallback only)
  float* a3 = a2 + 524288;                // 1048576
  // main-path regions
  unsigned short* Bg = (unsigned short*)(wsf + 1966080);  // 10,616,832 float-slots
  float* part = wsf + 1966080 + 10616832;                 // 2,097,152
  uint32_t* Eg = (uint32_t*)(wsf + 14680064);             // 4,718,592
  float* El4 = wsf + 1966080;   // 12 f32/elem -> [1966080, 14549504), L4 only
  float* wl4 = h;               // h dead on main path after linear
  // RACE FIX (round 5): p4 must NOT alias El4. part lies inside El4's span;
  // use the Eg region instead (dead after L3 gemm, starts at 14680064 >= 14549504).
  float* p4  = wsf + 14680064;

  const size_t baseFloats = 1966080;
  size_t availFloats = ws_size / 4 > baseFloats ? ws_size / 4 - baseFloats : 0;
  const size_t mainNeed = 10616832ull + 2097152ull + 4718592ull;  // 17.4M

  if (availFloats >= mainNeed) {
    linear_pack_kernel<<<512, 256, 0, stream>>>(x, lin_w, lin_b, h, Eg, 1);

    // L1: CIN=512 COUT=256 4x4, SK=8
    prep_bpack<4608, 256><<<41472, 256, 0, stream>>>(bw1, sw1, ss1, Bg);
    gemm_mfma<512, 256, 4, 4, 8>
        <<<dim3(16, 4, 8), 256, 0, stream>>>(Eg, Bg, part);
    reduce_pe_pack<256, 4, 4><<<1024, 256, 0, stream>>>(part, Eg, 8);

    // L2: CIN=256 COUT=128 8x8, SK=4
    prep_bpack<2304, 128><<<10368, 256, 0, stream>>>(bw2, sw2, ss2, Bg);
    gemm_mfma<256, 128, 8, 8, 4>
        <<<dim3(64, 2, 4), 256, 0, stream>>>(Eg, Bg, part);
    reduce_pe_pack<128, 8, 8><<<2048, 256, 0, stream>>>(part, Eg, 4);

    // L3: CIN=128 COUT=64 16x16, SK=2
    prep_bpack<1152, 64><<<2592, 256, 0, stream>>>(bw3, sw3, ss3, Bg);
    gemm_mfma<128, 64, 16, 16, 2>
        <<<dim3(256, 1, 2), 256, 0, stream>>>(Eg, Bg, part);
    reduce_p<64, 16, 16><<<4096, 256, 0, stream>>>(part, a3, 2);

    // L4
    prep_wl4<<<61, 256, 0, stream>>>(bw4, sw4, ss4, wl4);
    l4_expand<<<4096, 256, 0, stream>>>(a3, El4);
    kan_l4_v3<<<1024, 256, 0, stream>>>(El4, wl4, p4);
    reduce_tanh_l4<<<768, 256, 0, stream>>>(p4, (float*)d_out);
  } else {
    // round-1 proven fallback (needs ~16.3 MB)
    float* partOld = a3 + 1048576;
    linear_pack_kernel<<<512, 256, 0, stream>>>(x, lin_w, lin_b, h, nullptr, 0);
    kan_gemm<512, 256, 4, 4, 64, 8>
        <<<dim3(16, 4, 8), 256, 0, stream>>>(h, bw1, sw1, ss1, partOld);
    reduce_partials_old<256, 4, 4, 8><<<1024, 256, 0, stream>>>(partOld, a1);
    kan_gemm<256, 128, 8, 8, 64, 2>
        <<<dim3(64, 2, 2), 256, 0, stream>>>(a1, bw2, sw2, ss2, partOld);
    reduce_partials_old<128, 8, 8, 2><<<2048, 256, 0, stream>>>(partOld, a2);
    kan_gemm<128, 64, 16, 16, 64, 1>
        <<<dim3(256, 1, 1), 256, 0, stream>>>(a2, bw3, sw3, ss3, a3);
    kan_l4_split<<<1024, 256, 0, stream>>>(a3, bw4, sw4, ss4, partOld);
    reduce_tanh_l4<<<768, 256, 0, stream>>>(partOld, (float*)d_out);
  }
}